// Round 4
// baseline (256.107 us; speedup 1.0000x reference)
//
#include <hip/hip_runtime.h>
#include <stdint.h>

#define M_ROWS 32768
#define I_DIM 256
#define H_DIM 512
#define C_DIM 1024
#define O_DIM 512

typedef __attribute__((ext_vector_type(8))) short bf16x8;
typedef __attribute__((ext_vector_type(4))) float f32x4;

// ---------------------------------------------------------------------------
// 2-plane RNE split: x = hi + mid + r2, |r2| <= 2^-18 |x|.
// ---------------------------------------------------------------------------
__device__ __forceinline__ ushort bf16_rne(float f) {
    unsigned u = __float_as_uint(f);
    unsigned r = u + 0x7FFFu + ((u >> 16) & 1u);
    return (ushort)(r >> 16);
}
__device__ __forceinline__ float bf16_f32(ushort h) {
    return __uint_as_float(((unsigned)h) << 16);
}
__device__ __forceinline__ void split2(float f, ushort& hi, ushort& mid) {
    hi = bf16_rne(f);
    mid = bf16_rne(f - bf16_f32(hi));
}

__device__ __forceinline__ void async_ld16(const void* g, void* l) {
    __builtin_amdgcn_global_load_lds(
        (const __attribute__((address_space(1))) void*)g,
        (__attribute__((address_space(3))) void*)l, 16, 0, 0);
}

// Monotone packing: larger packed <=> (larger value, then smaller col index)
__device__ __forceinline__ unsigned long long packvi(float v, int col) {
    unsigned u = __float_as_uint(v);
    u = (u & 0x80000000u) ? ~u : (u | 0x80000000u);
    return ((unsigned long long)u << 32) | (unsigned)(~col);
}

// Swizzle: within each 64B k32-group of a row, 16B chunk kc sits at slot
// (kc + (row>>1)) & 3. Makes stride-64B fragment ds_read_b128 conflict-free
// while keeping rows DMA-contiguous (global_load_lds can't pad).
__device__ __forceinline__ int slot_of(int kc, int row) {
    return (kc + ((row >> 1) & 3)) & 3;
}

// ---------------------------------------------------------------------------
// prep: weight splits (permuted layout) + log-softmax table + part[] zero.
// ---------------------------------------------------------------------------
__global__ __launch_bounds__(256)
void prep(const float* __restrict__ W1, ushort* __restrict__ w1h, ushort* __restrict__ w1m,
          const float* __restrict__ W2, ushort* __restrict__ w2h, ushort* __restrict__ w2m,
          const float* __restrict__ Wo, const float* __restrict__ bo,
          float* __restrict__ LS, unsigned long long* __restrict__ part) {
    __shared__ float sred[4];
    const int b = blockIdx.x;
    const int t = threadIdx.x;
    if (b < 320) {
        const int isW1 = (b < 64);
        const float* W = isW1 ? W1 : W2;
        ushort* hh = isW1 ? w1h : w2h;
        ushort* mm = isW1 ? w1m : w2m;
        const int K = isW1 ? I_DIM : H_DIM;
        const int cpr = K >> 3;                       // chunks per row
        int gid = (isW1 ? b : b - 64) * 256 + t;      // chunk id
        int row = gid / cpr;
        int rem = gid - row * cpr;
        int g = rem >> 2, kc = rem & 3;
        float4 v0 = *(const float4*)(W + (size_t)gid * 8);
        float4 v1 = *(const float4*)(W + (size_t)gid * 8 + 4);
        __align__(16) ushort h[8], m[8];
        float f[8];
        *(float4*)&f[0] = v0; *(float4*)&f[4] = v1;
        #pragma unroll
        for (int j = 0; j < 8; ++j) split2(f[j], h[j], m[j]);
        size_t dst = (size_t)row * K + g * 32 + slot_of(kc, row) * 8;
        *(uint4*)(hh + dst) = *(uint4*)h;
        *(uint4*)(mm + dst) = *(uint4*)m;
    } else if (b < 1344) {
        const int j = b - 320;
        float l0 = Wo[(size_t)t * C_DIM + j] + bo[t];
        float l1 = Wo[(size_t)(t + 256) * C_DIM + j] + bo[t + 256];

        float mx = fmaxf(l0, l1);
        #pragma unroll
        for (int off = 1; off < 64; off <<= 1)
            mx = fmaxf(mx, __shfl_xor(mx, off, 64));
        if ((t & 63) == 0) sred[t >> 6] = mx;
        __syncthreads();
        mx = fmaxf(fmaxf(sred[0], sred[1]), fmaxf(sred[2], sred[3]));
        __syncthreads();

        float s = expf(l0 - mx) + expf(l1 - mx);
        #pragma unroll
        for (int off = 1; off < 64; off <<= 1)
            s += __shfl_xor(s, off, 64);
        if ((t & 63) == 0) sred[t >> 6] = s;
        __syncthreads();
        s = sred[0] + sred[1] + sred[2] + sred[3];

        float lse = mx + logf(s);
        LS[(size_t)j * O_DIM + t] = l0 - lse;
        LS[(size_t)j * O_DIM + t + 256] = l1 - lse;
    } else {
        part[(b - 1344) * 256 + t] = 0ull;
    }
}

// ---------------------------------------------------------------------------
// GEMM1 (MFMA, 3 products): H = relu(X @ W1^T + b1) -> two bf16 planes in
// permuted layout, stored via LDS-staged coalesced uint4 stores.
// (round-0 proven structure, 4 blocks/CU)
// ---------------------------------------------------------------------------
__global__ __launch_bounds__(256, 4)
void gemm1_mfma(const float* __restrict__ X, const ushort* __restrict__ W1h,
                const ushort* __restrict__ W1m, const float* __restrict__ b1,
                ushort* __restrict__ Hh, ushort* __restrict__ Hm) {
    __shared__ __align__(16) ushort LB[16384];   // 32KB: A planes, B planes / stage
    ushort* As0 = LB;
    ushort* As1 = LB + 4096;
    ushort* Bs0 = LB + 8192;
    ushort* Bs1 = LB + 12288;

    const int tid = threadIdx.x;
    const int lane = tid & 63, wave = tid >> 6;
    const int wm = wave >> 1, wn = wave & 1;
    const int lcol = lane & 15, quad = lane >> 4;
    const int mBase = blockIdx.x * 128;
    const int nBase = blockIdx.y * 128;
    const int s_row = tid >> 1, s_half = tid & 1;
    const int bplane = wave >> 1;
    const ushort* wp = bplane ? W1m : W1h;
    const int brow0 = (wave & 1) * 64;
    const int lrow = lane >> 2, lk = (lane & 3) * 8;

    f32x4 acc[4][4];
    #pragma unroll
    for (int i = 0; i < 4; ++i)
        #pragma unroll
        for (int j = 0; j < 4; ++j)
            acc[i][j] = (f32x4){0.f, 0.f, 0.f, 0.f};

    int aoff[4], boff[4];
    #pragma unroll
    for (int t = 0; t < 4; ++t) {
        int ra = wm * 64 + t * 16 + lcol;
        int rb = wn * 64 + t * 16 + lcol;
        aoff[t] = ra * 32 + slot_of(quad, ra) * 8;
        boff[t] = rb * 32 + slot_of(quad, rb) * 8;
    }
    // A staging write slots (chunks kc = s_half*2, s_half*2+1)
    const int sl0 = slot_of(s_half * 2,     s_row);
    const int sl1 = slot_of(s_half * 2 + 1, s_row);

    for (int ks = 0; ks < I_DIM / 32; ++ks) {
        const int k0 = ks * 32;
        const float* ap = X + (size_t)(mBase + s_row) * I_DIM + k0 + s_half * 16;
        float4 f0 = ((const float4*)ap)[0];
        float4 f1 = ((const float4*)ap)[1];
        float4 f2 = ((const float4*)ap)[2];
        float4 f3 = ((const float4*)ap)[3];

        __syncthreads();

        // B planes via DMA (permuted layout is already in the global buffers)
        #pragma unroll
        for (int i = 0; i < 4; ++i) {
            int r = brow0 + i * 16;
            const ushort* g = wp + (size_t)(nBase + r + lrow) * I_DIM + k0 + lk;
            async_ld16(g, (bplane ? Bs1 : Bs0) + r * 32);
        }

        // A: split fp32 -> 2 bf16 planes, swizzled LDS writes
        float f[16];
        *(float4*)&f[0] = f0; *(float4*)&f[4] = f1;
        *(float4*)&f[8] = f2; *(float4*)&f[12] = f3;
        bf16x8 h0, h1, m0, m1;
        #pragma unroll
        for (int j = 0; j < 8; ++j) {
            ushort hu, mu;
            split2(f[j], hu, mu);
            h0[j] = (short)hu; m0[j] = (short)mu;
            split2(f[j + 8], hu, mu);
            h1[j] = (short)hu; m1[j] = (short)mu;
        }
        *(bf16x8*)&As0[s_row * 32 + sl0 * 8] = h0;
        *(bf16x8*)&As0[s_row * 32 + sl1 * 8] = h1;
        *(bf16x8*)&As1[s_row * 32 + sl0 * 8] = m0;
        *(bf16x8*)&As1[s_row * 32 + sl1 * 8] = m1;

        __syncthreads();

        bf16x8 af[4][2];
        #pragma unroll
        for (int mt = 0; mt < 4; ++mt) {
            af[mt][0] = *(const bf16x8*)&As0[aoff[mt]];
            af[mt][1] = *(const bf16x8*)&As1[aoff[mt]];
        }
        #pragma unroll
        for (int nt = 0; nt < 4; ++nt) {
            bf16x8 bh = *(const bf16x8*)&Bs0[boff[nt]];
            bf16x8 bm = *(const bf16x8*)&Bs1[boff[nt]];
            #pragma unroll
            for (int mt = 0; mt < 4; ++mt) {
                f32x4 a = acc[mt][nt];
                a = __builtin_amdgcn_mfma_f32_16x16x32_bf16(af[mt][1], bh, a, 0, 0, 0);
                a = __builtin_amdgcn_mfma_f32_16x16x32_bf16(af[mt][0], bm, a, 0, 0, 0);
                a = __builtin_amdgcn_mfma_f32_16x16x32_bf16(af[mt][0], bh, a, 0, 0, 0);
                acc[mt][nt] = a;
            }
        }
    }

    // ---- epilogue: bias+relu+split, LDS-staged in permuted-global layout,
    //      then coalesced uint4 copies. Two passes (hi, mid); acc stays live.
    #pragma unroll
    for (int plane = 0; plane < 2; ++plane) {
        __syncthreads();   // previous LDS use complete
        #pragma unroll
        for (int nt = 0; nt < 4; ++nt) {
            int colRel = wn * 64 + nt * 16 + lcol;
            int g = colRel >> 5, kc = (colRel >> 3) & 3, pos = colRel & 7;
            float bias = b1[nBase + colRel];
            #pragma unroll
            for (int mt = 0; mt < 4; ++mt) {
                #pragma unroll
                for (int r = 0; r < 4; ++r) {
                    int rowRel = wm * 64 + mt * 16 + quad * 4 + r;
                    float v = fmaxf(acc[mt][nt][r] + bias, 0.f);
                    ushort hu, mu;
                    split2(v, hu, mu);
                    LB[rowRel * 128 + g * 32 + slot_of(kc, rowRel) * 8 + pos]
                        = plane ? mu : hu;
                }
            }
        }
        __syncthreads();
        ushort* dstp = plane ? Hm : Hh;
        #pragma unroll
        for (int l = 0; l < 8; ++l) {
            int c = l * 256 + tid;
            int row = c >> 4, idx = c & 15;
            *(uint4*)(dstp + (size_t)(mBase + row) * H_DIM + nBase + idx * 8)
                = *(const uint4*)&LB[row * 128 + idx * 8];
        }
    }
}

// ---------------------------------------------------------------------------
// GEMM2: 256x256 tile, 512 threads (8 waves = 2m x 4n), BK=32, double-buffered
// 128KB LDS. 4-phase schedule per K-step (m201 template): each phase = one
// C-quadrant (4mt x 2nt x 3 products = 24 MFMA) with
// {12 ds_read -> DMA prefetch -> barrier -> lgkmcnt(0) -> MFMA -> barrier}.
// Next-tile DMAs issued 4+4 in phases 0/1 -> >=2.5 phases of slack before the
// tile-boundary vmcnt(0). Argmax epilogue.
// ---------------------------------------------------------------------------
__global__ __launch_bounds__(512, 2)
void gemm2_mfma(const ushort* __restrict__ Hh, const ushort* __restrict__ Hm,
                const ushort* __restrict__ W2h, const ushort* __restrict__ W2m,
                const float* __restrict__ b2,
                unsigned long long* __restrict__ part) {
    __shared__ __align__(16) ushort As[2][2][8192];   // [buf][plane][256*32] 64KB
    __shared__ __align__(16) ushort Bs[2][2][8192];   // 64KB
    const int tid = threadIdx.x;
    const int lane = tid & 63, wave = tid >> 6;
    const int wm = wave >> 2, wn = wave & 3;          // 2m x 4n wave grid
    const int lcol = lane & 15, quad = lane >> 4;
    const int lrow = lane >> 2, lk = (lane & 3) * 8;

    // XCD swizzle: grid 512 = 128 mT x 4 nT. XCD x = d&7 owns mT [x*16,x*16+16),
    // nT fastest -> W2 (2MB) L2-resident, A-tile reused across the 4 nT.
    const int d = blockIdx.x;
    const int l = d >> 3;
    const int mT = ((d & 7) << 4) + (l >> 2);
    const int nT = l & 3;
    const int mBase = mT * 256;
    const int nBase = nT * 256;

    // staging role: m_id 0=Ah 1=Am 2=Bh 3=Bm; each wave stages 128 rows (8KB)
    const int m_id = wave >> 1;
    const int shalf = wave & 1;
    const ushort* gsrc;
    ushort* l0;
    ushort* l1;
    switch (m_id) {
        case 0:  gsrc = Hh  + (size_t)mBase * H_DIM; l0 = &As[0][0][0]; l1 = &As[1][0][0]; break;
        case 1:  gsrc = Hm  + (size_t)mBase * H_DIM; l0 = &As[0][1][0]; l1 = &As[1][1][0]; break;
        case 2:  gsrc = W2h + (size_t)nBase * H_DIM; l0 = &Bs[0][0][0]; l1 = &Bs[1][0][0]; break;
        default: gsrc = W2m + (size_t)nBase * H_DIM; l0 = &Bs[0][1][0]; l1 = &Bs[1][1][0]; break;
    }
    l0 += shalf * 4096;
    l1 += shalf * 4096;
    const ushort* gks = gsrc + (size_t)(shalf * 128 + lrow) * H_DIM + lk;

    f32x4 acc[8][4];
    #pragma unroll
    for (int i = 0; i < 8; ++i)
        #pragma unroll
        for (int j = 0; j < 4; ++j)
            acc[i][j] = (f32x4){0.f, 0.f, 0.f, 0.f};

    int aoff[8], boff[4];
    #pragma unroll
    for (int t = 0; t < 8; ++t) {
        int ra = wm * 128 + t * 16 + lcol;
        aoff[t] = ra * 32 + slot_of(quad, ra) * 8;
    }
    #pragma unroll
    for (int t = 0; t < 4; ++t) {
        int rb = wn * 64 + t * 16 + lcol;
        boff[t] = rb * 32 + slot_of(quad, rb) * 8;
    }

    // stage half a tile-slab (4 of this wave's 8 rows-chunks)
    auto stage4 = [&](ushort* lb, int k0, int jb) {
        #pragma unroll
        for (int j = 0; j < 4; ++j)
            async_ld16(gks + k0 + (size_t)((jb + j) * 16) * H_DIM,
                       lb + (jb + j) * 512);
    };

    // prologue: tile 0 -> buf 0
    stage4(l0, 0, 0);
    stage4(l0, 0, 4);
    asm volatile("s_waitcnt vmcnt(0)" ::: "memory");
    __builtin_amdgcn_s_barrier();
    __builtin_amdgcn_sched_barrier(0);

    const int NK = H_DIM / 32;   // 16
    #pragma unroll 2
    for (int ks = 0; ks < NK; ++ks) {
        const int cur = ks & 1;
        ushort* nxt = cur ? l0 : l1;
        const bool more = (ks + 1 < NK);

        #pragma unroll
        for (int ph = 0; ph < 4; ++ph) {
            const int mh = ph >> 1, nh = ph & 1;   // quadrant

            // ds-load this phase's fragments (12 x ds_read_b128)
            bf16x8 ah[4], am[4], bh[2], bm[2];
            #pragma unroll
            for (int mt = 0; mt < 4; ++mt) {
                ah[mt] = *(const bf16x8*)&As[cur][0][aoff[mh * 4 + mt]];
                am[mt] = *(const bf16x8*)&As[cur][1][aoff[mh * 4 + mt]];
            }
            #pragma unroll
            for (int nt = 0; nt < 2; ++nt) {
                bh[nt] = *(const bf16x8*)&Bs[cur][0][boff[nh * 2 + nt]];
                bm[nt] = *(const bf16x8*)&Bs[cur][1][boff[nh * 2 + nt]];
            }

            // prefetch next tile: 4 DMAs in ph0, 4 in ph1
            if (more && ph < 2) stage4(nxt, (ks + 1) * 32, ph * 4);

            __builtin_amdgcn_s_barrier();
            asm volatile("s_waitcnt lgkmcnt(0)" ::: "memory");
            __builtin_amdgcn_sched_barrier(0);

            __builtin_amdgcn_s_setprio(1);
            #pragma unroll
            for (int nt = 0; nt < 2; ++nt) {
                #pragma unroll
                for (int mt = 0; mt < 4; ++mt) {
                    f32x4 a = acc[mh * 4 + mt][nh * 2 + nt];
                    a = __builtin_amdgcn_mfma_f32_16x16x32_bf16(am[mt], bh[nt], a, 0, 0, 0);
                    a = __builtin_amdgcn_mfma_f32_16x16x32_bf16(ah[mt], bm[nt], a, 0, 0, 0);
                    a = __builtin_amdgcn_mfma_f32_16x16x32_bf16(ah[mt], bh[nt], a, 0, 0, 0);
                    acc[mh * 4 + mt][nh * 2 + nt] = a;
                }
            }
            __builtin_amdgcn_s_setprio(0);

            if (ph == 3) {
                if (more) {
                    // next tile's 8 DMAs (issued ph0/ph1, >=2.5 phases ago)
                    asm volatile("s_waitcnt vmcnt(0)" ::: "memory");
                    __builtin_amdgcn_s_barrier();
                    __builtin_amdgcn_sched_barrier(0);
                }
                // last tile: no barrier needed, epilogue is register-only
            } else {
                __builtin_amdgcn_s_barrier();
                __builtin_amdgcn_sched_barrier(0);
            }
        }
    }

    // ---- epilogue: bias + argmax over this 256-col block -> atomicMax ----
    float bias[4];
    #pragma unroll
    for (int nt = 0; nt < 4; ++nt)
        bias[nt] = b2[nBase + wn * 64 + nt * 16 + lcol];

    #pragma unroll
    for (int mt = 0; mt < 8; ++mt) {
        #pragma unroll
        for (int r = 0; r < 4; ++r) {
            unsigned long long best = 0ull;
            #pragma unroll
            for (int nt = 0; nt < 4; ++nt) {
                int col = nBase + wn * 64 + nt * 16 + lcol;
                float v = acc[mt][nt][r] + bias[nt];
                unsigned long long p = packvi(v, col);
                if (p > best) best = p;
            }
            #pragma unroll
            for (int off = 1; off < 16; off <<= 1) {
                unsigned long long o = __shfl_xor((long long)best, off, 64);
                if (o > best) best = o;
            }
            if (lcol == 0) {
                int row = mBase + wm * 128 + mt * 16 + quad * 4 + r;
                atomicMax(&part[row], best);
            }
        }
    }
}

// out[row,:] = LS[jstar(part[row]), :]; 2 rows per block
__global__ __launch_bounds__(256)
void gather_out(const unsigned long long* __restrict__ part,
                const float* __restrict__ LS, float* __restrict__ out) {
    const int tid = threadIdx.x;
    const int row = blockIdx.x * 2 + (tid >> 7);
    const int q = tid & 127;
    unsigned long long best = part[row];
    unsigned u = (unsigned)(best >> 32);
    float v = (u & 0x80000000u) ? __uint_as_float(u ^ 0x80000000u)
                                : __uint_as_float(~u);
    int col = (int)(~(unsigned)best) & (C_DIM - 1);
    int j = (v > 0.f) ? col : 0;   // all-nonpositive c => relu zeros => top_k picks 0
    float4 val = ((const float4*)LS)[(size_t)j * 128 + q];
    ((float4*)out)[(size_t)row * 128 + q] = val;
}

extern "C" void kernel_launch(void* const* d_in, const int* in_sizes, int n_in,
                              void* d_out, int out_size, void* d_ws, size_t ws_size,
                              hipStream_t stream) {
    const float* x     = (const float*)d_in[0];
    const float* i2m_w = (const float*)d_in[2];
    const float* i2m_b = (const float*)d_in[3];
    const float* m2h_w = (const float*)d_in[4];
    const float* m2h_b = (const float*)d_in[5];
    const float* h2o_w = (const float*)d_in[6];
    const float* h2o_b = (const float*)d_in[7];
    float* out = (float*)d_out;

    // ws layout (bytes):
    //   [0, 256K)        w1 hi plane   [256K, 512K)  w1 mid plane
    //   [512K, 1.5M)     w2 hi plane   [1.5M, 2.5M)  w2 mid plane
    //   [2.5M, 4.5M)     LS table (1024 x 512 fp32)
    //   [4.5M, 4.75M)    part: 32768 u64 (atomicMax targets, zeroed in prep)
    char* ws = (char*)d_ws;
    ushort* w1h = (ushort*)(ws);
    ushort* w1m = (ushort*)(ws + 262144);
    ushort* w2h = (ushort*)(ws + 524288);
    ushort* w2m = (ushort*)(ws + 1572864);
    float*  LS  = (float*)(ws + 2621440);
    unsigned long long* part = (unsigned long long*)(ws + 4718592);

    // H planes live in d_out (2 x 32768*512 ushort = 64MB = exactly out_size*4B)
    ushort* Hh = (ushort*)d_out;
    ushort* Hm = Hh + (size_t)M_ROWS * H_DIM;

    prep<<<1472, 256, 0, stream>>>(i2m_w, w1h, w1m, m2h_w, w2h, w2m,
                                   h2o_w, h2o_b, LS, part);
    gemm1_mfma<<<dim3(M_ROWS / 128, H_DIM / 128), 256, 0, stream>>>(
        x, w1h, w1m, i2m_b, Hh, Hm);
    gemm2_mfma<<<(M_ROWS / 256) * (C_DIM / 256), 512, 0, stream>>>(
        Hh, Hm, w2h, w2m, m2h_b, part);
    gather_out<<<M_ROWS / 2, 256, 0, stream>>>(part, LS, out);
}

// Round 5
// 242.049 us; speedup vs baseline: 1.0581x; 1.0581x over previous
//
#include <hip/hip_runtime.h>
#include <stdint.h>

#define M_ROWS 32768
#define I_DIM 256
#define H_DIM 512
#define C_DIM 1024
#define O_DIM 512

typedef __attribute__((ext_vector_type(8))) short bf16x8;
typedef __attribute__((ext_vector_type(4))) float f32x4;

// ---------------------------------------------------------------------------
// 2-plane RNE split: x = hi + mid + r2, |r2| <= 2^-18 |x|.
// ---------------------------------------------------------------------------
__device__ __forceinline__ ushort bf16_rne(float f) {
    unsigned u = __float_as_uint(f);
    unsigned r = u + 0x7FFFu + ((u >> 16) & 1u);
    return (ushort)(r >> 16);
}
__device__ __forceinline__ float bf16_f32(ushort h) {
    return __uint_as_float(((unsigned)h) << 16);
}
__device__ __forceinline__ void split2(float f, ushort& hi, ushort& mid) {
    hi = bf16_rne(f);
    mid = bf16_rne(f - bf16_f32(hi));
}

__device__ __forceinline__ void async_ld16(const void* g, void* l) {
    __builtin_amdgcn_global_load_lds(
        (const __attribute__((address_space(1))) void*)g,
        (__attribute__((address_space(3))) void*)l, 16, 0, 0);
}

// Monotone packing: larger packed <=> (larger value, then smaller col index)
__device__ __forceinline__ unsigned long long packvi(float v, int col) {
    unsigned u = __float_as_uint(v);
    u = (u & 0x80000000u) ? ~u : (u | 0x80000000u);
    return ((unsigned long long)u << 32) | (unsigned)(~col);
}

// Swizzle: within each 64B k32-group of a row, 16B chunk kc sits at slot
// (kc + (row>>1)) & 3. Makes stride-64B fragment ds_read_b128 conflict-free
// while keeping rows DMA-contiguous (global_load_lds can't pad).
__device__ __forceinline__ int slot_of(int kc, int row) {
    return (kc + ((row >> 1) & 3)) & 3;
}

// ---------------------------------------------------------------------------
// prep: weight splits (permuted layout) + log-softmax table + part[] zero.
// ---------------------------------------------------------------------------
__global__ __launch_bounds__(256)
void prep(const float* __restrict__ W1, ushort* __restrict__ w1h, ushort* __restrict__ w1m,
          const float* __restrict__ W2, ushort* __restrict__ w2h, ushort* __restrict__ w2m,
          const float* __restrict__ Wo, const float* __restrict__ bo,
          float* __restrict__ LS, unsigned long long* __restrict__ part) {
    __shared__ float sred[4];
    const int b = blockIdx.x;
    const int t = threadIdx.x;
    if (b < 320) {
        const int isW1 = (b < 64);
        const float* W = isW1 ? W1 : W2;
        ushort* hh = isW1 ? w1h : w2h;
        ushort* mm = isW1 ? w1m : w2m;
        const int K = isW1 ? I_DIM : H_DIM;
        const int cpr = K >> 3;                       // chunks per row
        int gid = (isW1 ? b : b - 64) * 256 + t;      // chunk id
        int row = gid / cpr;
        int rem = gid - row * cpr;
        int g = rem >> 2, kc = rem & 3;
        float4 v0 = *(const float4*)(W + (size_t)gid * 8);
        float4 v1 = *(const float4*)(W + (size_t)gid * 8 + 4);
        __align__(16) ushort h[8], m[8];
        float f[8];
        *(float4*)&f[0] = v0; *(float4*)&f[4] = v1;
        #pragma unroll
        for (int j = 0; j < 8; ++j) split2(f[j], h[j], m[j]);
        size_t dst = (size_t)row * K + g * 32 + slot_of(kc, row) * 8;
        *(uint4*)(hh + dst) = *(uint4*)h;
        *(uint4*)(mm + dst) = *(uint4*)m;
    } else if (b < 1344) {
        const int j = b - 320;
        float l0 = Wo[(size_t)t * C_DIM + j] + bo[t];
        float l1 = Wo[(size_t)(t + 256) * C_DIM + j] + bo[t + 256];

        float mx = fmaxf(l0, l1);
        #pragma unroll
        for (int off = 1; off < 64; off <<= 1)
            mx = fmaxf(mx, __shfl_xor(mx, off, 64));
        if ((t & 63) == 0) sred[t >> 6] = mx;
        __syncthreads();
        mx = fmaxf(fmaxf(sred[0], sred[1]), fmaxf(sred[2], sred[3]));
        __syncthreads();

        float s = expf(l0 - mx) + expf(l1 - mx);
        #pragma unroll
        for (int off = 1; off < 64; off <<= 1)
            s += __shfl_xor(s, off, 64);
        if ((t & 63) == 0) sred[t >> 6] = s;
        __syncthreads();
        s = sred[0] + sred[1] + sred[2] + sred[3];

        float lse = mx + logf(s);
        LS[(size_t)j * O_DIM + t] = l0 - lse;
        LS[(size_t)j * O_DIM + t + 256] = l1 - lse;
    } else {
        part[(b - 1344) * 256 + t] = 0ull;
    }
}

// ---------------------------------------------------------------------------
// GEMM1: 256x256 tile, 512 threads (8 waves = 2m x 4n), BK=32, double-buffered
// 128KB LDS (single SMEM block, reused as 128KB epilogue staging).
// Per K-step: issue X reg-loads + B-plane DMAs for step k+1, compute step k
// (96 MFMA/wave), then split X -> A planes into the other buffer (VALU
// overlaps MFMA tail), one counted drain + one barrier. K/product order
// bit-identical to the round-0 gemm1 -> identical H planes.
// ---------------------------------------------------------------------------
__global__ __launch_bounds__(512, 2)
void gemm1_mfma(const float* __restrict__ X, const ushort* __restrict__ W1h,
                const ushort* __restrict__ W1m, const float* __restrict__ b1,
                ushort* __restrict__ Hh, ushort* __restrict__ Hm) {
    __shared__ __align__(16) ushort SMEM[65536];   // 128KB
    // partition: A[buf][plane] = SMEM + buf*16384 + plane*8192        (64KB)
    //            B[buf][plane] = SMEM + 32768 + buf*16384 + plane*8192 (64KB)

    const int tid = threadIdx.x;
    const int lane = tid & 63, wave = tid >> 6;
    const int wm = wave >> 2, wn = wave & 3;          // 2m x 4n wave grid
    const int lcol = lane & 15, quad = lane >> 4;
    const int lrow = lane >> 2, lk = (lane & 3) * 8;

    // XCD swizzle: grid 256 = 128 mT x 2 nT; XCD d&7 owns 16 contiguous mT.
    const int d = blockIdx.x;
    const int q = d >> 3;
    const int mT = ((d & 7) << 4) + (q >> 1);
    const int nT = q & 1;
    const int mBase = mT * 256;
    const int nBase = nT * 256;

    // A staging (X fp32 -> 2 bf16 planes): 512 thr cover 256 rows x 2 halves
    const int s_row = tid >> 1, s_half = tid & 1;
    const int sl0 = slot_of(s_half * 2,     s_row);
    const int sl1 = slot_of(s_half * 2 + 1, s_row);
    const float* xrow = X + (size_t)(mBase + s_row) * I_DIM + s_half * 16;

    // B staging (DMA): plane = wave>>2, rows [(wave&3)*64, +64)
    const int bplane = wave >> 2;
    const int brow0 = (wave & 3) * 64;
    const ushort* wp = bplane ? W1m : W1h;
    const ushort* gks = wp + (size_t)(nBase + brow0 + lrow) * I_DIM + lk;

    f32x4 acc[8][4];
    #pragma unroll
    for (int i = 0; i < 8; ++i)
        #pragma unroll
        for (int j = 0; j < 4; ++j)
            acc[i][j] = (f32x4){0.f, 0.f, 0.f, 0.f};

    int aoff[8], boff[4];
    #pragma unroll
    for (int t = 0; t < 8; ++t) {
        int ra = wm * 128 + t * 16 + lcol;
        aoff[t] = ra * 32 + slot_of(quad, ra) * 8;
    }
    #pragma unroll
    for (int t = 0; t < 4; ++t) {
        int rb = wn * 64 + t * 16 + lcol;
        boff[t] = rb * 32 + slot_of(quad, rb) * 8;
    }

    auto loadX = [&](float* f, int k0) {
        const float* ap = xrow + k0;
        *(float4*)&f[0]  = ((const float4*)ap)[0];
        *(float4*)&f[4]  = ((const float4*)ap)[1];
        *(float4*)&f[8]  = ((const float4*)ap)[2];
        *(float4*)&f[12] = ((const float4*)ap)[3];
    };
    auto stageB = [&](int buf, int k0) {
        ushort* bb = SMEM + 32768 + buf * 16384 + bplane * 8192 + brow0 * 32;
        #pragma unroll
        for (int j = 0; j < 4; ++j)
            async_ld16(gks + k0 + (size_t)(j * 16) * I_DIM, bb + j * 512);
    };
    auto writeA = [&](int buf, const float* f) {
        ushort* a0 = SMEM + buf * 16384;
        ushort* a1 = a0 + 8192;
        bf16x8 h0, h1, m0, m1;
        #pragma unroll
        for (int j = 0; j < 8; ++j) {
            ushort hu, mu;
            split2(f[j], hu, mu);
            h0[j] = (short)hu; m0[j] = (short)mu;
            split2(f[j + 8], hu, mu);
            h1[j] = (short)hu; m1[j] = (short)mu;
        }
        *(bf16x8*)&a0[s_row * 32 + sl0 * 8] = h0;
        *(bf16x8*)&a0[s_row * 32 + sl1 * 8] = h1;
        *(bf16x8*)&a1[s_row * 32 + sl0 * 8] = m0;
        *(bf16x8*)&a1[s_row * 32 + sl1 * 8] = m1;
    };

    // prologue: tile 0 -> buf 0
    {
        float fx[16];
        loadX(fx, 0);
        stageB(0, 0);
        writeA(0, fx);   // compiler waits the X reg-loads only (issued older)
    }
    asm volatile("s_waitcnt lgkmcnt(0)" ::: "memory");
    asm volatile("s_waitcnt vmcnt(0)" ::: "memory");
    __builtin_amdgcn_s_barrier();
    __builtin_amdgcn_sched_barrier(0);

    const int NK = I_DIM / 32;   // 8
    #pragma unroll 2
    for (int ks = 0; ks < NK; ++ks) {
        const int cur = ks & 1;
        const bool more = (ks + 1 < NK);
        const ushort* Ac0 = SMEM + cur * 16384;
        const ushort* Ac1 = Ac0 + 8192;
        const ushort* Bc0 = SMEM + 32768 + cur * 16384;
        const ushort* Bc1 = Bc0 + 8192;

        float fn[16];
        if (more) {
            loadX(fn, (ks + 1) * 32);        // X reg-loads in flight over MFMA
            stageB(cur ^ 1, (ks + 1) * 32);  // 4 DMA into other buffer
            __builtin_amdgcn_sched_barrier(0);
        }

        // B fragments: read once, live across both m-halves
        bf16x8 bh[4], bm[4];
        #pragma unroll
        for (int nt = 0; nt < 4; ++nt) {
            bh[nt] = *(const bf16x8*)&Bc0[boff[nt]];
            bm[nt] = *(const bf16x8*)&Bc1[boff[nt]];
        }
        #pragma unroll
        for (int half = 0; half < 2; ++half) {
            bf16x8 ah[4], am[4];
            #pragma unroll
            for (int mt = 0; mt < 4; ++mt) {
                ah[mt] = *(const bf16x8*)&Ac0[aoff[half * 4 + mt]];
                am[mt] = *(const bf16x8*)&Ac1[aoff[half * 4 + mt]];
            }
            __builtin_amdgcn_s_setprio(1);
            #pragma unroll
            for (int nt = 0; nt < 4; ++nt) {
                #pragma unroll
                for (int mt = 0; mt < 4; ++mt) {
                    f32x4 a = acc[half * 4 + mt][nt];
                    a = __builtin_amdgcn_mfma_f32_16x16x32_bf16(am[mt], bh[nt], a, 0, 0, 0);
                    a = __builtin_amdgcn_mfma_f32_16x16x32_bf16(ah[mt], bm[nt], a, 0, 0, 0);
                    a = __builtin_amdgcn_mfma_f32_16x16x32_bf16(ah[mt], bh[nt], a, 0, 0, 0);
                    acc[half * 4 + mt][nt] = a;
                }
            }
            __builtin_amdgcn_s_setprio(0);
        }

        if (more) writeA(cur ^ 1, fn);   // split VALU overlaps MFMA issue
        asm volatile("s_waitcnt lgkmcnt(0)" ::: "memory");  // reads+writes done
        if (more)
            asm volatile("s_waitcnt vmcnt(0)" ::: "memory"); // B DMAs landed
        __builtin_amdgcn_s_barrier();
        __builtin_amdgcn_sched_barrier(0);
    }

    // ---- epilogue: bias+relu+split, staged in permuted-global layout across
    //      the full 128KB SMEM (256x256 ushort per plane), coalesced uint4 out.
    #pragma unroll
    for (int plane = 0; plane < 2; ++plane) {
        __syncthreads();   // previous SMEM use complete
        #pragma unroll
        for (int nt = 0; nt < 4; ++nt) {
            int colRel = wn * 64 + nt * 16 + lcol;
            int g = colRel >> 5, kc = (colRel >> 3) & 3, pos = colRel & 7;
            float bias = b1[nBase + colRel];
            #pragma unroll
            for (int mt = 0; mt < 8; ++mt) {
                #pragma unroll
                for (int r = 0; r < 4; ++r) {
                    int rowRel = wm * 128 + mt * 16 + quad * 4 + r;
                    float v = fmaxf(acc[mt][nt][r] + bias, 0.f);
                    ushort hu, mu;
                    split2(v, hu, mu);
                    SMEM[rowRel * 256 + g * 32 + slot_of(kc, rowRel) * 8 + pos]
                        = plane ? mu : hu;
                }
            }
        }
        __syncthreads();
        ushort* dstp = plane ? Hm : Hh;
        #pragma unroll
        for (int l2 = 0; l2 < 16; ++l2) {
            int c = l2 * 512 + tid;
            int row = c >> 5, idx = c & 31;
            *(uint4*)(dstp + (size_t)(mBase + row) * H_DIM + nBase + idx * 8)
                = *(const uint4*)&SMEM[row * 256 + idx * 8];
        }
    }
}

// ---------------------------------------------------------------------------
// GEMM2: 256x256 tile, 512 threads (8 waves = 2m x 4n), BK=32, double-buffered
// 128KB LDS, depth-1 counted pipeline: tile k+1's 8 DMAs are issued at the top
// of step k and drained (vmcnt(0)) at its bottom -- a full compute phase
// (~3700cy of MFMA) of slack. One barrier per K-step. Argmax epilogue.
// (round-3 proven structure, 100.4 us)
// ---------------------------------------------------------------------------
__global__ __launch_bounds__(512, 2)
void gemm2_mfma(const ushort* __restrict__ Hh, const ushort* __restrict__ Hm,
                const ushort* __restrict__ W2h, const ushort* __restrict__ W2m,
                const float* __restrict__ b2,
                unsigned long long* __restrict__ part) {
    __shared__ __align__(16) ushort As[2][2][8192];   // [buf][plane][256*32] 64KB
    __shared__ __align__(16) ushort Bs[2][2][8192];   // 64KB
    const int tid = threadIdx.x;
    const int lane = tid & 63, wave = tid >> 6;
    const int wm = wave >> 2, wn = wave & 3;          // 2m x 4n wave grid
    const int lcol = lane & 15, quad = lane >> 4;
    const int lrow = lane >> 2, lk = (lane & 3) * 8;

    // XCD swizzle: grid 512 = 128 mT x 4 nT. XCD x = d&7 owns mT [x*16,x*16+16),
    // nT fastest -> W2 (2MB) L2-resident, A-tile reused across the 4 nT.
    const int d = blockIdx.x;
    const int l = d >> 3;
    const int mT = ((d & 7) << 4) + (l >> 2);
    const int nT = l & 3;
    const int mBase = mT * 256;
    const int nBase = nT * 256;

    // staging role: m_id 0=Ah 1=Am 2=Bh 3=Bm; each wave stages 128 rows (8KB)
    const int m_id = wave >> 1;
    const int shalf = wave & 1;
    const ushort* gsrc;
    ushort* l0;
    ushort* l1;
    switch (m_id) {
        case 0:  gsrc = Hh  + (size_t)mBase * H_DIM; l0 = &As[0][0][0]; l1 = &As[1][0][0]; break;
        case 1:  gsrc = Hm  + (size_t)mBase * H_DIM; l0 = &As[0][1][0]; l1 = &As[1][1][0]; break;
        case 2:  gsrc = W2h + (size_t)nBase * H_DIM; l0 = &Bs[0][0][0]; l1 = &Bs[1][0][0]; break;
        default: gsrc = W2m + (size_t)nBase * H_DIM; l0 = &Bs[0][1][0]; l1 = &Bs[1][1][0]; break;
    }
    l0 += shalf * 4096;
    l1 += shalf * 4096;
    const ushort* gks = gsrc + (size_t)(shalf * 128 + lrow) * H_DIM + lk;

    f32x4 acc[8][4];
    #pragma unroll
    for (int i = 0; i < 8; ++i)
        #pragma unroll
        for (int j = 0; j < 4; ++j)
            acc[i][j] = (f32x4){0.f, 0.f, 0.f, 0.f};

    int aoff[8], boff[4];
    #pragma unroll
    for (int t = 0; t < 8; ++t) {
        int ra = wm * 128 + t * 16 + lcol;
        aoff[t] = ra * 32 + slot_of(quad, ra) * 8;
    }
    #pragma unroll
    for (int t = 0; t < 4; ++t) {
        int rb = wn * 64 + t * 16 + lcol;
        boff[t] = rb * 32 + slot_of(quad, rb) * 8;
    }

    auto stage = [&](ushort* lb, int k0) {
        #pragma unroll
        for (int j = 0; j < 8; ++j)
            async_ld16(gks + k0 + (size_t)(j * 16) * H_DIM, lb + j * 512);
    };

    // prologue: tile 0 -> buf 0
    stage(l0, 0);
    asm volatile("s_waitcnt vmcnt(0)" ::: "memory");
    __builtin_amdgcn_s_barrier();
    __builtin_amdgcn_sched_barrier(0);

    const int NK = H_DIM / 32;   // 16
    #pragma unroll 2
    for (int ks = 0; ks < NK; ++ks) {
        const int cur = ks & 1;
        if (ks < NK - 1) {
            stage(cur ? l0 : l1, (ks + 1) * 32);   // 8 DMA into other buffer
            __builtin_amdgcn_sched_barrier(0);     // keep issue early
        }

        // B fragments: read once, live across both m-halves
        bf16x8 bh[4], bm[4];
        #pragma unroll
        for (int nt = 0; nt < 4; ++nt) {
            bh[nt] = *(const bf16x8*)&Bs[cur][0][boff[nt]];
            bm[nt] = *(const bf16x8*)&Bs[cur][1][boff[nt]];
        }
        #pragma unroll
        for (int half = 0; half < 2; ++half) {
            bf16x8 ah[4], am[4];
            #pragma unroll
            for (int mt = 0; mt < 4; ++mt) {
                ah[mt] = *(const bf16x8*)&As[cur][0][aoff[half * 4 + mt]];
                am[mt] = *(const bf16x8*)&As[cur][1][aoff[half * 4 + mt]];
            }
            __builtin_amdgcn_s_setprio(1);
            #pragma unroll
            for (int nt = 0; nt < 4; ++nt) {
                #pragma unroll
                for (int mt = 0; mt < 4; ++mt) {
                    f32x4 a = acc[half * 4 + mt][nt];
                    a = __builtin_amdgcn_mfma_f32_16x16x32_bf16(am[mt], bh[nt], a, 0, 0, 0);
                    a = __builtin_amdgcn_mfma_f32_16x16x32_bf16(ah[mt], bm[nt], a, 0, 0, 0);
                    a = __builtin_amdgcn_mfma_f32_16x16x32_bf16(ah[mt], bh[nt], a, 0, 0, 0);
                    acc[half * 4 + mt][nt] = a;
                }
            }
            __builtin_amdgcn_s_setprio(0);
        }

        if (ks < NK - 1)
            asm volatile("s_waitcnt vmcnt(0)" ::: "memory");  // tile k+1 landed
        __builtin_amdgcn_s_barrier();       // all reads of buf[cur] consumed
        __builtin_amdgcn_sched_barrier(0);  // nothing crosses the boundary
    }

    // ---- epilogue: bias + argmax over this 256-col block -> atomicMax ----
    float bias[4];
    #pragma unroll
    for (int nt = 0; nt < 4; ++nt)
        bias[nt] = b2[nBase + wn * 64 + nt * 16 + lcol];

    #pragma unroll
    for (int mt = 0; mt < 8; ++mt) {
        #pragma unroll
        for (int r = 0; r < 4; ++r) {
            unsigned long long best = 0ull;
            #pragma unroll
            for (int nt = 0; nt < 4; ++nt) {
                int col = nBase + wn * 64 + nt * 16 + lcol;
                float v = acc[mt][nt][r] + bias[nt];
                unsigned long long p = packvi(v, col);
                if (p > best) best = p;
            }
            #pragma unroll
            for (int off = 1; off < 16; off <<= 1) {
                unsigned long long o = __shfl_xor((long long)best, off, 64);
                if (o > best) best = o;
            }
            if (lcol == 0) {
                int row = mBase + wm * 128 + mt * 16 + quad * 4 + r;
                atomicMax(&part[row], best);
            }
        }
    }
}

// out[row,:] = LS[jstar(part[row]), :]; 2 rows per block
__global__ __launch_bounds__(256)
void gather_out(const unsigned long long* __restrict__ part,
                const float* __restrict__ LS, float* __restrict__ out) {
    const int tid = threadIdx.x;
    const int row = blockIdx.x * 2 + (tid >> 7);
    const int q = tid & 127;
    unsigned long long best = part[row];
    unsigned u = (unsigned)(best >> 32);
    float v = (u & 0x80000000u) ? __uint_as_float(u ^ 0x80000000u)
                                : __uint_as_float(~u);
    int col = (int)(~(unsigned)best) & (C_DIM - 1);
    int j = (v > 0.f) ? col : 0;   // all-nonpositive c => relu zeros => top_k picks 0
    float4 val = ((const float4*)LS)[(size_t)j * 128 + q];
    ((float4*)out)[(size_t)row * 128 + q] = val;
}

extern "C" void kernel_launch(void* const* d_in, const int* in_sizes, int n_in,
                              void* d_out, int out_size, void* d_ws, size_t ws_size,
                              hipStream_t stream) {
    const float* x     = (const float*)d_in[0];
    const float* i2m_w = (const float*)d_in[2];
    const float* i2m_b = (const float*)d_in[3];
    const float* m2h_w = (const float*)d_in[4];
    const float* m2h_b = (const float*)d_in[5];
    const float* h2o_w = (const float*)d_in[6];
    const float* h2o_b = (const float*)d_in[7];
    float* out = (float*)d_out;

    // ws layout (bytes):
    //   [0, 256K)        w1 hi plane   [256K, 512K)  w1 mid plane
    //   [512K, 1.5M)     w2 hi plane   [1.5M, 2.5M)  w2 mid plane
    //   [2.5M, 4.5M)     LS table (1024 x 512 fp32)
    //   [4.5M, 4.75M)    part: 32768 u64 (atomicMax targets, zeroed in prep)
    char* ws = (char*)d_ws;
    ushort* w1h = (ushort*)(ws);
    ushort* w1m = (ushort*)(ws + 262144);
    ushort* w2h = (ushort*)(ws + 524288);
    ushort* w2m = (ushort*)(ws + 1572864);
    float*  LS  = (float*)(ws + 2621440);
    unsigned long long* part = (unsigned long long*)(ws + 4718592);

    // H planes live in d_out (2 x 32768*512 ushort = 64MB = exactly out_size*4B)
    ushort* Hh = (ushort*)d_out;
    ushort* Hm = Hh + (size_t)M_ROWS * H_DIM;

    prep<<<1472, 256, 0, stream>>>(i2m_w, w1h, w1m, m2h_w, w2h, w2m,
                                   h2o_w, h2o_b, LS, part);
    gemm1_mfma<<<(M_ROWS / 256) * (H_DIM / 256), 512, 0, stream>>>(
        x, w1h, w1m, i2m_b, Hh, Hm);
    gemm2_mfma<<<(M_ROWS / 256) * (C_DIM / 256), 512, 0, stream>>>(
        Hh, Hm, w2h, w2m, m2h_b, part);
    gather_out<<<M_ROWS / 2, 256, 0, stream>>>(part, LS, out);
}